// Round 2
// 293.982 us; speedup vs baseline: 1.0052x; 1.0052x over previous
//
#include <hip/hip_runtime.h>

// Problem constants (match reference)
#define BATCH   8
#define LEN     2048
#define DMODEL  512
#define T_MAX   200.0f

// clang-native 4-float vector: __builtin_nontemporal_store requires a native
// vector type, not HIP's float4 class. Same 16B layout/alignment.
typedef float floatx4 __attribute__((ext_vector_type(4)));

// Fused kernel:
//  - blocks [0, EMB_BLOCKS): embedding [B,L,DMODEL]. 4 rows per 256-thread
//    block (two 128-thread row-groups x 2 rows each); per-thread float4 store.
//    inv_pos factors computed once per thread (not per row).
//  - blocks [EMB_BLOCKS, EMB_BLOCKS + B*L): scores + t_diff row kernel,
//    identical math to the verified 295us kernel.
// All output stores are non-temporal (streaming, never re-read): 302 MB of
// writes should not allocate in the 4MB/XCD L2s.
// Embed blocks are placed FIRST so the short blocks overlap the scores ramp
// instead of serializing behind 16384 score blocks in a second launch.

#define EMB_BLOCKS 4096                  // 16384 rows / 4 rows per block
#define SC_BLOCKS  (BATCH * LEN)         // 16384

__global__ __launch_bounds__(256) void fused_encoder_kernel(
    const float* __restrict__ t,        // [B*L]
    const float* __restrict__ ls_p,     // [1]
    const float* __restrict__ gate_p,   // [2]
    float* __restrict__ scores,         // [B,L,L]
    float* __restrict__ emb,            // [B,L,DMODEL]
    float* __restrict__ tdiff)          // [B,L,L]
{
    const int bid = blockIdx.x;
    const int tid = threadIdx.x;

    if (bid < EMB_BLOCKS) {
        // ---------------- embedding path ----------------
        const int d0 = (tid & 127) * 4;              // dim offset, 128 thr/row
        const int r0 = bid * 4 + (tid >> 7) * 2;     // this group's first row
        const float c = -9.210340371976184f * (2.0f / (float)DMODEL); // -ln(1e4)*2/D

        // 10000^(-2*dim/D) for the 4 dims this thread owns — row-invariant
        const float ip0 = __expf(c * (float)(d0 + 0));
        const float ip1 = __expf(c * (float)(d0 + 1));
        const float ip2 = __expf(c * (float)(d0 + 2));
        const float ip3 = __expf(c * (float)(d0 + 3));

#pragma unroll
        for (int r = 0; r < 2; ++r) {
            const int row = r0 + r;
            const float tv = t[row];
            floatx4 e;
            e.x = __sinf(tv * ip0);   // even dim -> sin
            e.y = __cosf(tv * ip1);   // odd dim  -> cos
            e.z = __sinf(tv * ip2);
            e.w = __cosf(tv * ip3);
            __builtin_nontemporal_store(
                e, (floatx4*)(emb + (size_t)row * DMODEL + d0));
        }
        return;
    }

    // ---------------- scores + t_diff path ----------------
    const int row = bid - EMB_BLOCKS;    // b*LEN + i
    const int b   = row >> 11;           // / LEN
    const int i   = row & (LEN - 1);
    const int c0  = tid * 4;             // cols [0,1024)
    const int c1  = 1024 + c0;           // cols [1024,2048)

    const float ti = t[row];

    // learned params (wave-uniform)
    const float ls      = log1pf(__expf(ls_p[0]));            // softplus
    const float inv_ls2 = 1.0f / (ls * ls);
    const float l = 1.0f / (1.0f + __expf(-gate_p[0]));       // sigmoid
    const float s = 1.0f / (1.0f + __expf(-gate_p[1]));
    const float inv_s2 = 2.0f / s;                            // for 2*u
    const float invT   = 1.0f / T_MAX;

    const float* trow = t + b * LEN;
    float4 ta = *(const float4*)(trow + c0);
    float4 tb = *(const float4*)(trow + c1);
    float tj[8] = {ta.x, ta.y, ta.z, ta.w, tb.x, tb.y, tb.z, tb.w};
    int   col[8] = {c0, c0 + 1, c0 + 2, c0 + 3, c1, c1 + 1, c1 + 2, c1 + 3};

    float sc[8], td[8];
#pragma unroll
    for (int k = 0; k < 8; ++k) {
        float d  = ti - tj[k];
        float ad = fabsf(d);
        float kern = __expf(-ad * ad * inv_ls2);
        float u2 = (ad * invT - l) * inv_s2;                  // 2*(d/T-l)/s
        // 1 + tanh(u) == 2 * sigmoid(2u)
        float gate = __fdividef(2.0f, 1.0f + __expf(-u2));
        sc[k] = (col[k] <= i) ? kern * gate : 0.0f;
        td[k] = d;
    }

    size_t base = (size_t)row * LEN;
    floatx4 s0 = {sc[0], sc[1], sc[2], sc[3]};
    floatx4 s1 = {sc[4], sc[5], sc[6], sc[7]};
    floatx4 d0v = {td[0], td[1], td[2], td[3]};
    floatx4 d1v = {td[4], td[5], td[6], td[7]};
    __builtin_nontemporal_store(s0, (floatx4*)(scores + base + c0));
    __builtin_nontemporal_store(s1, (floatx4*)(scores + base + c1));
    __builtin_nontemporal_store(d0v, (floatx4*)(tdiff + base + c0));
    __builtin_nontemporal_store(d1v, (floatx4*)(tdiff + base + c1));
}

extern "C" void kernel_launch(void* const* d_in, const int* in_sizes, int n_in,
                              void* d_out, int out_size, void* d_ws, size_t ws_size,
                              hipStream_t stream) {
    // inputs: [0]=event_type (int, unused), [1]=event_time (f32, B*L),
    //         [2]=length_scale_param (f32,1), [3]=gate_params (f32,2)
    const float* t      = (const float*)d_in[1];
    const float* ls_p   = (const float*)d_in[2];
    const float* gate_p = (const float*)d_in[3];

    float* out = (float*)d_out;
    const size_t n_scores = (size_t)BATCH * LEN * LEN;    // 33554432
    const size_t n_emb    = (size_t)BATCH * LEN * DMODEL; // 8388608
    float* scores = out;
    float* emb    = out + n_scores;
    float* tdiff  = out + n_scores + n_emb;

    fused_encoder_kernel<<<EMB_BLOCKS + SC_BLOCKS, 256, 0, stream>>>(
        t, ls_p, gate_p, scores, emb, tdiff);
}